// Round 1
// baseline (310.501 us; speedup 1.0000x reference)
//
#include <hip/hip_runtime.h>

typedef float f32x4 __attribute__((ext_vector_type(4)));
typedef _Float16 h16x8 __attribute__((ext_vector_type(8)));
typedef _Float16 h16x4 __attribute__((ext_vector_type(4)));

#define GLOAD_LDS16(gp, lp) __builtin_amdgcn_global_load_lds(               \
    (const __attribute__((address_space(1))) void*)(gp),                    \
    (__attribute__((address_space(3))) void*)(lp), 16, 0, 0)

// ---------------------------------------------------------------------------
// cast x (f32) -> f16, 8 elems/thread
__global__ __launch_bounds__(256) void cast_x(const float* __restrict__ x,
                                              _Float16* __restrict__ xh) {
  long i = (long)blockIdx.x * 256 + threadIdx.x;  // 8-elem groups
  f32x4 a = *(const f32x4*)(x + i * 8);
  f32x4 b = *(const f32x4*)(x + i * 8 + 4);
  h16x8 h;
  h[0] = (_Float16)a[0]; h[1] = (_Float16)a[1];
  h[2] = (_Float16)a[2]; h[3] = (_Float16)a[3];
  h[4] = (_Float16)b[0]; h[5] = (_Float16)b[1];
  h[6] = (_Float16)b[2]; h[7] = (_Float16)b[3];
  *(h16x8*)(xh + i * 8) = h;
}

// ---------------------------------------------------------------------------
// transpose + cast weight: in f32 (K x N) row-major -> out f16 (N x K), *scale
__global__ __launch_bounds__(256) void tcw(const float* __restrict__ in,
                                           _Float16* __restrict__ out,
                                           int Kd, int Nd, float scale) {
  __shared__ float tile[64][65];
  const int t = threadIdx.x;
  const int k0 = blockIdx.y * 64, n0 = blockIdx.x * 64;
  const int tr = t >> 4, tc = (t & 15) * 4;
#pragma unroll
  for (int i = 0; i < 4; ++i) {
    int r = i * 16 + tr;
    f32x4 a = *(const f32x4*)(in + (long)(k0 + r) * Nd + n0 + tc);
    tile[r][tc + 0] = a[0]; tile[r][tc + 1] = a[1];
    tile[r][tc + 2] = a[2]; tile[r][tc + 3] = a[3];
  }
  __syncthreads();
#pragma unroll
  for (int i = 0; i < 4; ++i) {
    int r = i * 16 + tr;  // n index
    h16x4 h;
#pragma unroll
    for (int q = 0; q < 4; ++q) h[q] = (_Float16)(tile[tc + q][r] * scale);
    *(h16x4*)(out + (long)(n0 + r) * Kd + k0 + tc) = h;
  }
}

// ---------------------------------------------------------------------------
// f16 tile transpose: in (R x C) -> out (C x R), batched
__global__ __launch_bounds__(256) void trans16(const _Float16* __restrict__ in,
                                               _Float16* __restrict__ out,
                                               int R, int Cd, long ibatch, long obatch) {
  __shared__ _Float16 tile[64][72];
  in += (long)blockIdx.z * ibatch;
  out += (long)blockIdx.z * obatch;
  const int t = threadIdx.x;
  const int r0 = blockIdx.y * 64, c0 = blockIdx.x * 64;
  const int tr = t >> 3, tc8 = (t & 7) * 8;
#pragma unroll
  for (int i = 0; i < 2; ++i) {
    int r = i * 32 + tr;
    h16x8 a = *(const h16x8*)(in + (long)(r0 + r) * Cd + c0 + tc8);
    *(h16x8*)(&tile[r][tc8]) = a;
  }
  __syncthreads();
#pragma unroll
  for (int i = 0; i < 2; ++i) {
    int r = i * 32 + tr;  // c index
    h16x8 h;
#pragma unroll
    for (int q = 0; q < 8; ++q) h[q] = tile[tc8 + q][r];
    *(h16x8*)(out + (long)(c0 + r) * R + r0 + tc8) = h;
  }
}

// ---------------------------------------------------------------------------
// lambda_full = exp(sum lq1*lk1) - exp(sum lq2*lk2) + 0.8
__global__ __launch_bounds__(1024) void lambda_k(const float* __restrict__ lq1,
                                                 const float* __restrict__ lk1,
                                                 const float* __restrict__ lq2,
                                                 const float* __restrict__ lk2,
                                                 float* __restrict__ lam) {
  __shared__ float sh1[16], sh2[16];
  const int t = threadIdx.x;
  float p1 = lq1[t] * lk1[t];
  float p2 = lq2[t] * lk2[t];
#pragma unroll
  for (int off = 1; off < 64; off <<= 1) {
    p1 += __shfl_xor(p1, off);
    p2 += __shfl_xor(p2, off);
  }
  if ((t & 63) == 0) { sh1[t >> 6] = p1; sh2[t >> 6] = p2; }
  __syncthreads();
  if (t == 0) {
    float s1 = 0.f, s2 = 0.f;
    for (int i = 0; i < 16; ++i) { s1 += sh1[i]; s2 += sh2[i]; }
    lam[0] = __expf(s1) - __expf(s2) + 0.8f;
  }
}

// ---------------------------------------------------------------------------
// C(MxN) = A(MxK) @ B(NxK)^T, f16 inputs, CT output. 128x128 tile, BK=64,
// 4 waves (2x2), mfma_f32_16x16x32_f16, global_load_lds(16B) with XOR swizzle
// applied on the global source (LDS stays linear, G21).
template <typename CT>
__global__ __launch_bounds__(256, 2) void gemm_bt(
    const _Float16* __restrict__ A, const _Float16* __restrict__ B,
    CT* __restrict__ C, int K, int lda, int ldb, int ldc,
    long abatch, long bbatch, long cbatch) {
  __shared__ _Float16 As[128 * 64];
  __shared__ _Float16 Bs[128 * 64];
  const int t = threadIdx.x;
  const int lane = t & 63;
  const int wv = t >> 6;
  const int wr = wv >> 1, wc = wv & 1;
  const int lg = lane >> 4, l15 = lane & 15;
  const long z = blockIdx.z;
  const _Float16* Ab = A + z * abatch + (long)(blockIdx.y * 128) * lda;
  const _Float16* Bb = B + z * bbatch + (long)(blockIdx.x * 128) * ldb;
  CT* Cb = C + z * cbatch;

  f32x4 acc[4][4] = {};

  for (int kc = 0; kc < K; kc += 64) {
#pragma unroll
    for (int i = 0; i < 4; ++i) {
      int e = i * 256 + t;            // 16B chunk index, 0..1023
      int r = e >> 3, c8 = e & 7;     // LDS row / 16B slot
      int s8 = c8 ^ (r & 7);          // pre-swizzled global slot
      GLOAD_LDS16(Ab + (long)r * lda + kc + s8 * 8, As + e * 8);
      GLOAD_LDS16(Bb + (long)r * ldb + kc + s8 * 8, Bs + e * 8);
    }
    __syncthreads();
#pragma unroll
    for (int ks = 0; ks < 2; ++ks) {
      h16x8 af[4], bf[4];
#pragma unroll
      for (int m = 0; m < 4; ++m) {
        int r = wr * 64 + m * 16 + l15;
        int kb = (ks * 64 + lg * 16) ^ ((r & 7) << 4);
        af[m] = *(const h16x8*)((const char*)As + r * 128 + kb);
      }
#pragma unroll
      for (int n = 0; n < 4; ++n) {
        int r = wc * 64 + n * 16 + l15;
        int kb = (ks * 64 + lg * 16) ^ ((r & 7) << 4);
        bf[n] = *(const h16x8*)((const char*)Bs + r * 128 + kb);
      }
#pragma unroll
      for (int m = 0; m < 4; ++m)
#pragma unroll
        for (int n = 0; n < 4; ++n)
          acc[m][n] = __builtin_amdgcn_mfma_f32_16x16x32_f16(af[m], bf[n], acc[m][n], 0, 0, 0);
    }
    __syncthreads();
  }

  const int crow0 = blockIdx.y * 128 + wr * 64;
  const int ccol0 = blockIdx.x * 128 + wc * 64;
#pragma unroll
  for (int m = 0; m < 4; ++m)
#pragma unroll
    for (int n = 0; n < 4; ++n)
#pragma unroll
      for (int j = 0; j < 4; ++j) {
        int r = crow0 + m * 16 + lg * 4 + j;
        int c = ccol0 + n * 16 + l15;
        Cb[(long)r * ldc + c] = (CT)acc[m][n][j];
      }
}

// ---------------------------------------------------------------------------
// one wave per row: diff = softmax(S1) - lam * softmax(S2), f16 out
__global__ __launch_bounds__(256) void softmax_diff(const float* __restrict__ S1,
                                                    const float* __restrict__ S2,
                                                    _Float16* __restrict__ D,
                                                    const float* __restrict__ lamp) {
  const long row = (long)blockIdx.x * 4 + (threadIdx.x >> 6);
  const int lane = threadIdx.x & 63;
  const float lam = *lamp;
  const float* s1 = S1 + row * 2048;
  const float* s2 = S2 + row * 2048;
  float v1[32], v2[32];
  float m1 = -3e38f, m2 = -3e38f;
#pragma unroll
  for (int j = 0; j < 8; ++j) {
    f32x4 a = *(const f32x4*)(s1 + j * 256 + lane * 4);
    f32x4 b = *(const f32x4*)(s2 + j * 256 + lane * 4);
#pragma unroll
    for (int q = 0; q < 4; ++q) {
      v1[j * 4 + q] = a[q]; v2[j * 4 + q] = b[q];
      m1 = fmaxf(m1, a[q]); m2 = fmaxf(m2, b[q]);
    }
  }
#pragma unroll
  for (int off = 1; off < 64; off <<= 1) {
    m1 = fmaxf(m1, __shfl_xor(m1, off));
    m2 = fmaxf(m2, __shfl_xor(m2, off));
  }
  float l1 = 0.f, l2 = 0.f;
#pragma unroll
  for (int e = 0; e < 32; ++e) {
    v1[e] = __expf(v1[e] - m1); l1 += v1[e];
    v2[e] = __expf(v2[e] - m2); l2 += v2[e];
  }
#pragma unroll
  for (int off = 1; off < 64; off <<= 1) {
    l1 += __shfl_xor(l1, off);
    l2 += __shfl_xor(l2, off);
  }
  const float r1 = 1.f / l1, r2 = lam / l2;
  _Float16* d = D + row * 2048;
#pragma unroll
  for (int j = 0; j < 8; ++j) {
    h16x4 h;
#pragma unroll
    for (int q = 0; q < 4; ++q)
      h[q] = (_Float16)(v1[j * 4 + q] * r1 - v2[j * 4 + q] * r2);
    *(h16x4*)(d + j * 256 + lane * 4) = h;
  }
}

// ---------------------------------------------------------------------------
// one wave per row: out = O / sqrt(mean(O^2) + eps) * 0.2
__global__ __launch_bounds__(256) void rmsnorm(const float* __restrict__ O,
                                               float* __restrict__ out) {
  const long row = (long)blockIdx.x * 4 + (threadIdx.x >> 6);
  const int lane = threadIdx.x & 63;
  const float* o = O + row * 1024;
  f32x4 xv[4];
  float ss = 0.f;
#pragma unroll
  for (int j = 0; j < 4; ++j) {
    xv[j] = *(const f32x4*)(o + j * 256 + lane * 4);
#pragma unroll
    for (int q = 0; q < 4; ++q) ss += xv[j][q] * xv[j][q];
  }
#pragma unroll
  for (int off = 1; off < 64; off <<= 1) ss += __shfl_xor(ss, off);
  const float s = 0.2f * rsqrtf(ss * (1.f / 1024.f) + 1e-5f);
  float* po = out + row * 1024;
#pragma unroll
  for (int j = 0; j < 4; ++j) {
    f32x4 r;
#pragma unroll
    for (int q = 0; q < 4; ++q) r[q] = xv[j][q] * s;
    *(f32x4*)(po + j * 256 + lane * 4) = r;
  }
}

// ---------------------------------------------------------------------------
extern "C" void kernel_launch(void* const* d_in, const int* in_sizes, int n_in,
                              void* d_out, int out_size, void* d_ws, size_t ws_size,
                              hipStream_t stream) {
  const float* x   = (const float*)d_in[0];
  const float* wq  = (const float*)d_in[1];
  const float* wk  = (const float*)d_in[2];
  const float* wv  = (const float*)d_in[3];
  const float* lq1 = (const float*)d_in[4];
  const float* lk1 = (const float*)d_in[5];
  const float* lq2 = (const float*)d_in[6];
  const float* lk2 = (const float*)d_in[7];
  float* out = (float*)d_out;

  const size_t MB = 1ull << 20;
  char* ws = (char*)d_ws;
  _Float16* xh   = (_Float16*)(ws + 0);        // 16MB  8192x1024
  _Float16* wqT  = (_Float16*)(ws + 16 * MB);  // 4MB   2048x1024 (x scale)
  _Float16* wkT  = (_Float16*)(ws + 20 * MB);  // 4MB
  _Float16* wvT  = (_Float16*)(ws + 24 * MB);  // 2MB   1024x1024
  _Float16* q12  = (_Float16*)(ws + 26 * MB);  // 32MB  8192x2048
  _Float16* k12  = (_Float16*)(ws + 58 * MB);  // 32MB
  _Float16* v    = (_Float16*)(ws + 90 * MB);  // 16MB  8192x1024
  _Float16* vt   = (_Float16*)(ws + 106 * MB); // 16MB  4x1024x2048
  float*    S1   = (float*)(ws + 122 * MB);    // 64MB  4x2048x2048
  float*    S2   = (float*)(ws + 186 * MB);    // 64MB
  _Float16* diff = (_Float16*)(ws + 26 * MB);  // 32MB, reuses dead q12
  float*    opre = (float*)(ws + 58 * MB);     // 32MB, reuses dead k12
  float*    lam  = (float*)(ws + 250 * MB);    // 4B

  const float scale = 0.17677669529663689f;  // 1024^-0.25

  cast_x<<<4096, 256, 0, stream>>>(x, xh);
  tcw<<<dim3(32, 16), 256, 0, stream>>>(wq, wqT, 1024, 2048, scale);
  tcw<<<dim3(32, 16), 256, 0, stream>>>(wk, wkT, 1024, 2048, 1.0f);
  tcw<<<dim3(16, 16), 256, 0, stream>>>(wv, wvT, 1024, 1024, 1.0f);
  lambda_k<<<1, 1024, 0, stream>>>(lq1, lk1, lq2, lk2, lam);

  // projections: q12 = xh @ wqT^T, etc.
  gemm_bt<_Float16><<<dim3(16, 64, 1), 256, 0, stream>>>(xh, wqT, q12, 1024, 1024, 1024, 2048, 0, 0, 0);
  gemm_bt<_Float16><<<dim3(16, 64, 1), 256, 0, stream>>>(xh, wkT, k12, 1024, 1024, 1024, 2048, 0, 0, 0);
  gemm_bt<_Float16><<<dim3(8, 64, 1), 256, 0, stream>>>(xh, wvT, v, 1024, 1024, 1024, 1024, 0, 0, 0);

  // v (b,2048,1024) -> vt (b,1024,2048)
  trans16<<<dim3(16, 32, 4), 256, 0, stream>>>(v, vt, 2048, 1024, 2048l * 1024, 1024l * 2048);

  // S_p = q_p @ k_p^T (scale folded into q), f32 out
  gemm_bt<float><<<dim3(16, 16, 4), 256, 0, stream>>>(q12, k12, S1, 1024, 2048, 2048, 2048,
                                                      2048l * 2048, 2048l * 2048, 2048l * 2048);
  gemm_bt<float><<<dim3(16, 16, 4), 256, 0, stream>>>(q12 + 1024, k12 + 1024, S2, 1024, 2048, 2048, 2048,
                                                      2048l * 2048, 2048l * 2048, 2048l * 2048);

  softmax_diff<<<2048, 256, 0, stream>>>(S1, S2, diff, lam);

  // opre = diff @ vt^T  (K = 2048)
  gemm_bt<float><<<dim3(8, 16, 4), 256, 0, stream>>>(diff, vt, opre, 2048, 2048, 2048, 1024,
                                                     2048l * 2048, 1024l * 2048, 2048l * 1024);

  rmsnorm<<<2048, 256, 0, stream>>>(opre, out);
}